// Round 2
// baseline (415.155 us; speedup 1.0000x reference)
//
#include <hip/hip_runtime.h>
#include <hip/hip_fp16.h>
#include <stdint.h>

#define BB 512
#define TT 1024
#define II 15
#define HH 64
#define OO 11

typedef __fp16 half2v __attribute__((ext_vector_type(2)));
typedef _Float16 half8 __attribute__((ext_vector_type(8)));
typedef float floatx4 __attribute__((ext_vector_type(4)));
typedef int int4v __attribute__((ext_vector_type(4)));

union PK { int i; half2v h; float f; };

__device__ __forceinline__ half2v i2h2(int v) { PK u; u.i = v; return u.h; }
__device__ __forceinline__ int h22i(half2v v) { PK u; u.h = v; return u.i; }

__device__ __forceinline__ float FDOT2(half2v a, half2v b, float c) {
    return __builtin_amdgcn_fdot2(a, b, c, false);
}

// v4: TWO batch chains per wave, hand-interleaved.
// Total time = 1024 x per-step critical path; with one chain/wave the
// h ds_write -> 8x uniform ds_read_b128 round trip (~130cy) was fully
// exposed every step (437cy/step measured). Interleaving a second,
// independent chain in the same instruction stream covers chain A's
// broadcast latency with chain B's ~130cy of dot issue and vice versa:
// the h(t) broadcast reads are issued right after the h(t) write (DS pipe
// is in-order per wave -> RAW safe) and consumed a whole other-chain
// section later. No readlane/DPP path (R1 showed VALU->SGPR hazards make
// it a net loss); pure LDS broadcast, shared W registers across chains.
__global__ __launch_bounds__(64) void rnn_rec(
    const float* __restrict__ x, const float* __restrict__ W_ih,
    const float* __restrict__ b_ih, const float* __restrict__ W_hh,
    const float* __restrict__ b_hh, _Float16* __restrict__ hs,
    float* __restrict__ h_last)
{
    // [chain][buf][step*8 packed pairs]
    __shared__ __align__(16) int xbuf[2][2][64 * 8];
    __shared__ __align__(16) _Float16 hbuf[2][64];   // h_t per chain
    const int lane = threadIdx.x;
    const int bA = blockIdx.x * 2;
    const int bB = bA + 1;

    // recurrent weights (shared by both chains): whh[p] = (W[lane][2p], W[lane][2p+1])
    half2v whh[32];
#pragma unroll
    for (int p = 0; p < 32; ++p)
        whh[p] = __builtin_amdgcn_cvt_pkrtz(W_hh[lane * HH + 2 * p],
                                            W_hh[lane * HH + 2 * p + 1]);
    // input weights; pair 7 = (w14, bias) matching x pair (x14, 1.0)
    half2v wx[8];
#pragma unroll
    for (int j = 0; j < 7; ++j)
        wx[j] = __builtin_amdgcn_cvt_pkrtz(W_ih[lane * II + 2 * j],
                                           W_ih[lane * II + 2 * j + 1]);
    wx[7] = __builtin_amdgcn_cvt_pkrtz(W_ih[lane * II + 14],
                                       b_ih[lane] + b_hh[lane]);

    const float* xbA = x + (size_t)bA * TT * II;
    const float* xbB = x + (size_t)bB * TT * II;
    _Float16* hrowA = hs + (size_t)bA * TT * HH + lane;
    _Float16* hrowB = hs + (size_t)bB * TT * HH + lane;

    // stage chunk 0 of both chains: lane ts packs x[b][ts][0..14] -> 8 pairs
    {
        float cf[II];
#pragma unroll
        for (int i = 0; i < II; ++i) cf[i] = xbA[lane * II + i];
        int4v p0, p1;
        p0.x = h22i(__builtin_amdgcn_cvt_pkrtz(cf[0], cf[1]));
        p0.y = h22i(__builtin_amdgcn_cvt_pkrtz(cf[2], cf[3]));
        p0.z = h22i(__builtin_amdgcn_cvt_pkrtz(cf[4], cf[5]));
        p0.w = h22i(__builtin_amdgcn_cvt_pkrtz(cf[6], cf[7]));
        p1.x = h22i(__builtin_amdgcn_cvt_pkrtz(cf[8], cf[9]));
        p1.y = h22i(__builtin_amdgcn_cvt_pkrtz(cf[10], cf[11]));
        p1.z = h22i(__builtin_amdgcn_cvt_pkrtz(cf[12], cf[13]));
        p1.w = h22i(__builtin_amdgcn_cvt_pkrtz(cf[14], 1.0f));
        *(int4v*)&xbuf[0][0][lane * 8] = p0;
        *(int4v*)&xbuf[0][0][lane * 8 + 4] = p1;
#pragma unroll
        for (int i = 0; i < II; ++i) cf[i] = xbB[lane * II + i];
        p0.x = h22i(__builtin_amdgcn_cvt_pkrtz(cf[0], cf[1]));
        p0.y = h22i(__builtin_amdgcn_cvt_pkrtz(cf[2], cf[3]));
        p0.z = h22i(__builtin_amdgcn_cvt_pkrtz(cf[4], cf[5]));
        p0.w = h22i(__builtin_amdgcn_cvt_pkrtz(cf[6], cf[7]));
        p1.x = h22i(__builtin_amdgcn_cvt_pkrtz(cf[8], cf[9]));
        p1.y = h22i(__builtin_amdgcn_cvt_pkrtz(cf[10], cf[11]));
        p1.z = h22i(__builtin_amdgcn_cvt_pkrtz(cf[12], cf[13]));
        p1.w = h22i(__builtin_amdgcn_cvt_pkrtz(cf[14], 1.0f));
        *(int4v*)&xbuf[1][0][lane * 8] = p0;
        *(int4v*)&xbuf[1][0][lane * 8 + 4] = p1;
    }

    // xproj accumulators for step 0 (read back slot 0; wave-synchronous)
    float xaA[8], xaB[8];
    {
        int4v xv0 = *(const int4v*)&xbuf[0][0][0];
        int4v xv1 = *(const int4v*)&xbuf[0][0][4];
        xaA[0] = FDOT2(i2h2(xv0.x), wx[0], 0.0f);
        xaA[1] = FDOT2(i2h2(xv0.y), wx[1], 0.0f);
        xaA[2] = FDOT2(i2h2(xv0.z), wx[2], 0.0f);
        xaA[3] = FDOT2(i2h2(xv0.w), wx[3], 0.0f);
        xaA[4] = FDOT2(i2h2(xv1.x), wx[4], 0.0f);
        xaA[5] = FDOT2(i2h2(xv1.y), wx[5], 0.0f);
        xaA[6] = FDOT2(i2h2(xv1.z), wx[6], 0.0f);
        xaA[7] = FDOT2(i2h2(xv1.w), wx[7], 0.0f);
        xv0 = *(const int4v*)&xbuf[1][0][0];
        xv1 = *(const int4v*)&xbuf[1][0][4];
        xaB[0] = FDOT2(i2h2(xv0.x), wx[0], 0.0f);
        xaB[1] = FDOT2(i2h2(xv0.y), wx[1], 0.0f);
        xaB[2] = FDOT2(i2h2(xv0.z), wx[2], 0.0f);
        xaB[3] = FDOT2(i2h2(xv0.w), wx[3], 0.0f);
        xaB[4] = FDOT2(i2h2(xv1.x), wx[4], 0.0f);
        xaB[5] = FDOT2(i2h2(xv1.y), wx[5], 0.0f);
        xaB[6] = FDOT2(i2h2(xv1.z), wx[6], 0.0f);
        xaB[7] = FDOT2(i2h2(xv1.w), wx[7], 0.0f);
    }

    float hA = 0.0f, hB = 0.0f;
    // h(t-1) broadcast registers; h(-1) = 0 (no LDS read needed for t=0)
    int4v hbA[8], hbB[8];
#pragma unroll
    for (int q = 0; q < 8; ++q) { hbA[q] = int4v{0,0,0,0}; hbB[q] = int4v{0,0,0,0}; }

    // One chain's step. hb[] was prefetched at the end of this chain's
    // previous step; its latency was covered by the other chain's section.
    auto step = [&](int t, float (&xa)[8], int4v (&hb)[8],
                    _Float16* hbufc, const int* xbufc,
                    _Float16* hrow, float& h) __attribute__((always_inline)) {
        // x pairs for t+1: issue at section top, consumed at section bottom
        const int tn = t + 1;
        const int* xp = xbufc + ((tn >> 6) & 1) * 512 + (tn & 63) * 8;
        const int4v xv0 = *(const int4v*)xp;
        const int4v xv1 = *(const int4v*)(xp + 4);

        float a[8];
#pragma unroll
        for (int j = 0; j < 8; ++j) a[j] = xa[j];

        // 8 quads of packed pairs: hb[q] = pairs 4q..4q+3
#pragma unroll
        for (int q = 0; q < 8; ++q) {
            const int base = 4 * q;
            const int off = (q & 1) ? 4 : 0;
            a[off + 0] = FDOT2(i2h2(hb[q].x), whh[base + 0], a[off + 0]);
            a[off + 1] = FDOT2(i2h2(hb[q].y), whh[base + 1], a[off + 1]);
            a[off + 2] = FDOT2(i2h2(hb[q].z), whh[base + 2], a[off + 2]);
            a[off + 3] = FDOT2(i2h2(hb[q].w), whh[base + 3], a[off + 3]);
        }
        h = fmaxf(((a[0] + a[1]) + (a[2] + a[3])) +
                  ((a[4] + a[5]) + (a[6] + a[7])), 0.0f);
        const _Float16 hf = (_Float16)h;

        hbufc[lane] = hf;                  // publish h(t)   (ds_write_b16)
        // prefetch h(t) broadcast for t+1: DS pipe is in-order per wave, so
        // these reads see the write; latency hides under the other chain.
        const int4v* hb4 = (const int4v*)hbufc;
#pragma unroll
        for (int q = 0; q < 8; ++q) hb[q] = hb4[q];

        hrow[(size_t)t * HH] = hf;         // 128B contiguous global store

        // xproj for t+1 (xv ready by now; fills residual slack)
        xa[0] = FDOT2(i2h2(xv0.x), wx[0], 0.0f);
        xa[1] = FDOT2(i2h2(xv0.y), wx[1], 0.0f);
        xa[2] = FDOT2(i2h2(xv0.z), wx[2], 0.0f);
        xa[3] = FDOT2(i2h2(xv0.w), wx[3], 0.0f);
        xa[4] = FDOT2(i2h2(xv1.x), wx[4], 0.0f);
        xa[5] = FDOT2(i2h2(xv1.y), wx[5], 0.0f);
        xa[6] = FDOT2(i2h2(xv1.z), wx[6], 0.0f);
        xa[7] = FDOT2(i2h2(xv1.w), wx[7], 0.0f);
    };

    const int* xbufA = &xbuf[0][0][0];
    const int* xbufB = &xbuf[1][0][0];

    for (int tc = 0; tc < TT; tc += 64) {
        // global prefetch of the next chunk for both chains
        const int tnb = (tc + 64 < TT) ? (tc + 64) : tc;
        float nfA[II], nfB[II];
#pragma unroll
        for (int i = 0; i < II; ++i)
            nfA[i] = xbA[(size_t)(tnb + lane) * II + i];
#pragma unroll
        for (int i = 0; i < II; ++i)
            nfB[i] = xbB[(size_t)(tnb + lane) * II + i];

        for (int to = 0; to < 32; to += 8)
#pragma unroll
            for (int u = 0; u < 8; ++u) {
                step(tc + to + u, xaA, hbA, hbuf[0], xbufA, hrowA, hA);
                step(tc + to + u, xaB, hbB, hbuf[1], xbufB, hrowB, hB);
            }

        // commit prefetched chunks into the other xbuf half (t+1 reads touch
        // it only from ts=63; committed here at ts=32)
        {
            const int cb = ((tc >> 6) + 1) & 1;
            int4v p0, p1;
            p0.x = h22i(__builtin_amdgcn_cvt_pkrtz(nfA[0], nfA[1]));
            p0.y = h22i(__builtin_amdgcn_cvt_pkrtz(nfA[2], nfA[3]));
            p0.z = h22i(__builtin_amdgcn_cvt_pkrtz(nfA[4], nfA[5]));
            p0.w = h22i(__builtin_amdgcn_cvt_pkrtz(nfA[6], nfA[7]));
            p1.x = h22i(__builtin_amdgcn_cvt_pkrtz(nfA[8], nfA[9]));
            p1.y = h22i(__builtin_amdgcn_cvt_pkrtz(nfA[10], nfA[11]));
            p1.z = h22i(__builtin_amdgcn_cvt_pkrtz(nfA[12], nfA[13]));
            p1.w = h22i(__builtin_amdgcn_cvt_pkrtz(nfA[14], 1.0f));
            *(int4v*)&xbuf[0][cb][lane * 8] = p0;
            *(int4v*)&xbuf[0][cb][lane * 8 + 4] = p1;
            p0.x = h22i(__builtin_amdgcn_cvt_pkrtz(nfB[0], nfB[1]));
            p0.y = h22i(__builtin_amdgcn_cvt_pkrtz(nfB[2], nfB[3]));
            p0.z = h22i(__builtin_amdgcn_cvt_pkrtz(nfB[4], nfB[5]));
            p0.w = h22i(__builtin_amdgcn_cvt_pkrtz(nfB[6], nfB[7]));
            p1.x = h22i(__builtin_amdgcn_cvt_pkrtz(nfB[8], nfB[9]));
            p1.y = h22i(__builtin_amdgcn_cvt_pkrtz(nfB[10], nfB[11]));
            p1.z = h22i(__builtin_amdgcn_cvt_pkrtz(nfB[12], nfB[13]));
            p1.w = h22i(__builtin_amdgcn_cvt_pkrtz(nfB[14], 1.0f));
            *(int4v*)&xbuf[1][cb][lane * 8] = p0;
            *(int4v*)&xbuf[1][cb][lane * 8 + 4] = p1;
        }

        for (int to = 32; to < 64; to += 8)
#pragma unroll
            for (int u = 0; u < 8; ++u) {
                step(tc + to + u, xaA, hbA, hbuf[0], xbufA, hrowA, hA);
                step(tc + to + u, xaB, hbB, hbuf[1], xbufB, hrowB, hB);
            }
    }
    h_last[bA * HH + lane] = hA;
    h_last[bB * HH + lane] = hB;
}

// Decoder: one 16x16x64 tile per wave (16 consecutive (b,t) rows of one batch).
// hs read: 2KB contiguous per wave; out store: 704B contiguous per tile.
__global__ __launch_bounds__(256) void rnn_decode(
    const _Float16* __restrict__ hs, const float* __restrict__ W_dec,
    const float* __restrict__ b_dec, float* __restrict__ out)
{
    __shared__ __align__(16) _Float16 wl[16 * HH];
    const int tid = threadIdx.x;
    for (int i = tid; i < 16 * HH; i += 256)
        wl[i] = (_Float16)((i < OO * HH) ? W_dec[i] : 0.0f);
    __syncthreads();

    const int lane = tid & 63;
    const int wid  = tid >> 6;
    const int col  = lane & 15;
    const int quad = lane >> 4;
    const float bd = (col < OO) ? b_dec[col] : 0.0f;

    half8 bf0 = *(const half8*)&wl[col * HH + quad * 8];
    half8 bf1 = *(const half8*)&wl[col * HH + 32 + quad * 8];

    const size_t tile = (size_t)blockIdx.x * 4 + wid;   // 0..32767
    const size_t btb = tile * 16;
    const _Float16* ap = hs + (btb + (size_t)col) * HH + quad * 8;
    half8 a0 = *(const half8*)ap;
    half8 a1 = *(const half8*)(ap + 32);

    floatx4 acc = {0.0f, 0.0f, 0.0f, 0.0f};
    acc = __builtin_amdgcn_mfma_f32_16x16x32_f16(a0, bf0, acc, 0, 0, 0);
    acc = __builtin_amdgcn_mfma_f32_16x16x32_f16(a1, bf1, acc, 0, 0, 0);

    if (col < OO) {
#pragma unroll
        for (int r = 0; r < 4; ++r) {
            const size_t row = btb + (size_t)(quad * 4 + r);
            out[row * OO + col] = fmaxf(acc[r] + bd, 0.0f);
        }
    }
}

extern "C" void kernel_launch(void* const* d_in, const int* in_sizes, int n_in,
                              void* d_out, int out_size, void* d_ws, size_t ws_size,
                              hipStream_t stream) {
    const float* x     = (const float*)d_in[0];
    const float* W_ih  = (const float*)d_in[1];
    const float* b_ih  = (const float*)d_in[2];
    const float* W_hh  = (const float*)d_in[3];
    const float* b_hh  = (const float*)d_in[4];
    const float* W_dec = (const float*)d_in[5];
    const float* b_dec = (const float*)d_in[6];

    float* out    = (float*)d_out;
    float* h_last = out + (size_t)BB * TT * OO;   // second tuple output
    _Float16* hs  = (_Float16*)d_ws;              // [B][T][H] f16, 64 MiB

    rnn_rec<<<BB / 2, 64, 0, stream>>>(x, W_ih, b_ih, W_hh, b_hh, hs, h_last);
    rnn_decode<<<8192, 256, 0, stream>>>(hs, W_dec, b_dec, out);
}

// Round 3
// 371.207 us; speedup vs baseline: 1.1184x; 1.1184x over previous
//
#include <hip/hip_runtime.h>
#include <hip/hip_fp16.h>
#include <stdint.h>

#define BB 512
#define TT 1024
#define II 15
#define HH 64
#define OO 11

typedef __fp16 half2v __attribute__((ext_vector_type(2)));
typedef _Float16 half8 __attribute__((ext_vector_type(8)));
typedef float floatx4 __attribute__((ext_vector_type(4)));
typedef int int4v __attribute__((ext_vector_type(4)));

union PK { int i; half2v h; float f; };

__device__ __forceinline__ half2v i2h2(int v) { PK u; u.i = v; return u.h; }
__device__ __forceinline__ int h22i(half2v v) { PK u; u.h = v; return u.i; }

__device__ __forceinline__ float FDOT2(half2v a, half2v b, float c) {
    return __builtin_amdgcn_fdot2(a, b, c, false);
}

__device__ __forceinline__ float lane_xor1(float v) {
    PK u; u.f = v;
    // quad_perm(1,0,3,2) = 0xB1 : lane -> lane^1
    u.i = __builtin_amdgcn_mov_dpp(u.i, 0xB1, 0xF, 0xF, false);
    return u.f;
}

// v5: the R0 single-chain wave body (best measured: 437 cyc/step), but packed
// EIGHT independent chains per 512-thread block so each SIMD hosts TWO waves
// (wave i -> SIMD i%4). R0/R1/R2 all showed ~60% VALU issue duty with ~40%
// stall (LDS h-broadcast round trip + dep tail); at 0.5 waves/SIMD that stall
// was fully exposed, and source-level interleaving (R2) failed because the
// scheduler sank the prefetch reads back to their use. Hardware wave
// round-robin on the SIMD hides it instead: wall/step-pair ~ max(2*issue,
// issue+stall) ~ 506 cyc => ~253 cyc/chain-step. No cross-wave coupling: each
// wave owns its hbuf/xbuf slice, no __syncthreads anywhere.
__global__ __launch_bounds__(512) void rnn_rec(
    const float* __restrict__ x, const float* __restrict__ W_ih,
    const float* __restrict__ b_ih, const float* __restrict__ W_hh,
    const float* __restrict__ b_hh, _Float16* __restrict__ hs,
    float* __restrict__ h_last)
{
    // per-wave slices: xbuf[wid] = [buf][step][8 packed pairs], hbuf[wid] = h_t
    __shared__ __align__(16) int xbuf[8][2][64 * 8];   // 32 KiB
    __shared__ __align__(16) _Float16 hbuf[8][64];     // 1 KiB
    const int lane = threadIdx.x & 63;
    const int wid  = threadIdx.x >> 6;
    const int b = blockIdx.x * 8 + wid;

    // recurrent weights: whh[p] = (W_hh[lane][2p], W_hh[lane][2p+1])
    half2v whh[32];
#pragma unroll
    for (int p = 0; p < 32; ++p)
        whh[p] = __builtin_amdgcn_cvt_pkrtz(W_hh[lane * HH + 2 * p],
                                            W_hh[lane * HH + 2 * p + 1]);
    // input weights; pair 7 = (w14, bias) matching x pair (x14, 1.0)
    half2v wx[8];
#pragma unroll
    for (int j = 0; j < 7; ++j)
        wx[j] = __builtin_amdgcn_cvt_pkrtz(W_ih[lane * II + 2 * j],
                                           W_ih[lane * II + 2 * j + 1]);
    wx[7] = __builtin_amdgcn_cvt_pkrtz(W_ih[lane * II + 14],
                                       b_ih[lane] + b_hh[lane]);

    const float* xb = x + (size_t)b * TT * II;
    _Float16* hrow = hs + (size_t)b * TT * HH + lane;
    const int4v* hb4 = (const int4v*)hbuf[wid];

    // stage chunk 0 into xbuf[wid][0]: lane ts packs x[b][ts][0..14] -> 8 pairs
    {
        float cf[II];
#pragma unroll
        for (int i = 0; i < II; ++i) cf[i] = xb[lane * II + i];
        int4v p0, p1;
        p0.x = h22i(__builtin_amdgcn_cvt_pkrtz(cf[0], cf[1]));
        p0.y = h22i(__builtin_amdgcn_cvt_pkrtz(cf[2], cf[3]));
        p0.z = h22i(__builtin_amdgcn_cvt_pkrtz(cf[4], cf[5]));
        p0.w = h22i(__builtin_amdgcn_cvt_pkrtz(cf[6], cf[7]));
        p1.x = h22i(__builtin_amdgcn_cvt_pkrtz(cf[8], cf[9]));
        p1.y = h22i(__builtin_amdgcn_cvt_pkrtz(cf[10], cf[11]));
        p1.z = h22i(__builtin_amdgcn_cvt_pkrtz(cf[12], cf[13]));
        p1.w = h22i(__builtin_amdgcn_cvt_pkrtz(cf[14], 1.0f));
        *(int4v*)&xbuf[wid][0][lane * 8] = p0;
        *(int4v*)&xbuf[wid][0][lane * 8 + 4] = p1;
    }
    hbuf[wid][lane] = (_Float16)0.0f;    // h(-1) = 0

    // xproj accumulators for step 0 (read back slot 0; wave-synchronous)
    float xa[8];
    {
        const int4v xv0 = *(const int4v*)&xbuf[wid][0][0];
        const int4v xv1 = *(const int4v*)&xbuf[wid][0][4];
        xa[0] = FDOT2(i2h2(xv0.x), wx[0], 0.0f);
        xa[1] = FDOT2(i2h2(xv0.y), wx[1], 0.0f);
        xa[2] = FDOT2(i2h2(xv0.z), wx[2], 0.0f);
        xa[3] = FDOT2(i2h2(xv0.w), wx[3], 0.0f);
        xa[4] = FDOT2(i2h2(xv1.x), wx[4], 0.0f);
        xa[5] = FDOT2(i2h2(xv1.y), wx[5], 0.0f);
        xa[6] = FDOT2(i2h2(xv1.z), wx[6], 0.0f);
        xa[7] = FDOT2(i2h2(xv1.w), wx[7], 0.0f);
    }

    float h = 0.0f;
    int hpk = 0;   // packed (h[lane&~1], h[lane|1]) from previous step (h=0)

    auto step = [&](int t) {
        // LDS broadcast reads of h(t-1)[16..63]: 6 uniform-address b128
        int4v hb[6];
#pragma unroll
        for (int q = 0; q < 6; ++q) hb[q] = hb4[q + 2];

        // seed with precomputed xproj
        float a0 = xa[0], a1 = xa[1], a2 = xa[2], a3 = xa[3];
        float a4 = xa[4], a5 = xa[5], a6 = xa[6], a7 = xa[7];

        // register-broadcast path: h(t-1)[0..15] pairs live in even lanes'
        // hpk; readlane is wave-synchronous, no memory -> fills the DS stall
        a0 = FDOT2(i2h2(__builtin_amdgcn_readlane(hpk, 0)),  whh[0], a0);
        a1 = FDOT2(i2h2(__builtin_amdgcn_readlane(hpk, 2)),  whh[1], a1);
        a2 = FDOT2(i2h2(__builtin_amdgcn_readlane(hpk, 4)),  whh[2], a2);
        a3 = FDOT2(i2h2(__builtin_amdgcn_readlane(hpk, 6)),  whh[3], a3);
        a4 = FDOT2(i2h2(__builtin_amdgcn_readlane(hpk, 8)),  whh[4], a4);
        a5 = FDOT2(i2h2(__builtin_amdgcn_readlane(hpk, 10)), whh[5], a5);
        a6 = FDOT2(i2h2(__builtin_amdgcn_readlane(hpk, 12)), whh[6], a6);
        a7 = FDOT2(i2h2(__builtin_amdgcn_readlane(hpk, 14)), whh[7], a7);

        // LDS dots: round q consumes hb[q] (pairs 8+4q .. 11+4q)
#pragma unroll
        for (int q = 0; q < 6; ++q) {
            const int base = 8 + 4 * q;
            if ((q & 1) == 0) {
                a0 = FDOT2(i2h2(hb[q].x), whh[base + 0], a0);
                a1 = FDOT2(i2h2(hb[q].y), whh[base + 1], a1);
                a2 = FDOT2(i2h2(hb[q].z), whh[base + 2], a2);
                a3 = FDOT2(i2h2(hb[q].w), whh[base + 3], a3);
            } else {
                a4 = FDOT2(i2h2(hb[q].x), whh[base + 0], a4);
                a5 = FDOT2(i2h2(hb[q].y), whh[base + 1], a5);
                a6 = FDOT2(i2h2(hb[q].z), whh[base + 2], a6);
                a7 = FDOT2(i2h2(hb[q].w), whh[base + 3], a7);
            }
        }
        h = fmaxf(((a0 + a1) + (a2 + a3)) + ((a4 + a5) + (a6 + a7)), 0.0f);
        const _Float16 hf = (_Float16)h;
        hbuf[wid][lane] = hf;                  // publish h(t)  (DS op #7)

        // x pairs for step t+1 (DS ops #8,#9 — issued AFTER the h write)
        const int tn = t + 1;
        const int* xp = &xbuf[wid][(tn >> 6) & 1][(tn & 63) * 8];
        const int4v xv0 = *(const int4v*)xp;
        const int4v xv1 = *(const int4v*)(xp + 4);

        hrow[(size_t)t * HH] = hf;             // 128B contiguous global store

        // pack pair for next step's readlane path (off the DS pipe)
        hpk = h22i(__builtin_amdgcn_cvt_pkrtz(h, lane_xor1(h)));

        // xproj for t+1 (consumes xv late; fills residual stall)
        xa[0] = FDOT2(i2h2(xv0.x), wx[0], 0.0f);
        xa[1] = FDOT2(i2h2(xv0.y), wx[1], 0.0f);
        xa[2] = FDOT2(i2h2(xv0.z), wx[2], 0.0f);
        xa[3] = FDOT2(i2h2(xv0.w), wx[3], 0.0f);
        xa[4] = FDOT2(i2h2(xv1.x), wx[4], 0.0f);
        xa[5] = FDOT2(i2h2(xv1.y), wx[5], 0.0f);
        xa[6] = FDOT2(i2h2(xv1.z), wx[6], 0.0f);
        xa[7] = FDOT2(i2h2(xv1.w), wx[7], 0.0f);
    };

    for (int tc = 0; tc < TT; tc += 64) {
        // global prefetch of the next chunk (re-reads current on the last one)
        const int tnb = (tc + 64 < TT) ? (tc + 64) : tc;
        float nf[II];
#pragma unroll
        for (int i = 0; i < II; ++i)
            nf[i] = xb[(size_t)(tnb + lane) * II + i];

        for (int to = 0; to < 32; to += 8)
#pragma unroll
            for (int u = 0; u < 8; ++u) step(tc + to + u);

        // commit prefetched chunk into the other xbuf half (t+1 reads touch
        // it only from ts=63; committed here at ts=32)
        {
            const int cb = ((tc >> 6) + 1) & 1;
            int4v p0, p1;
            p0.x = h22i(__builtin_amdgcn_cvt_pkrtz(nf[0], nf[1]));
            p0.y = h22i(__builtin_amdgcn_cvt_pkrtz(nf[2], nf[3]));
            p0.z = h22i(__builtin_amdgcn_cvt_pkrtz(nf[4], nf[5]));
            p0.w = h22i(__builtin_amdgcn_cvt_pkrtz(nf[6], nf[7]));
            p1.x = h22i(__builtin_amdgcn_cvt_pkrtz(nf[8], nf[9]));
            p1.y = h22i(__builtin_amdgcn_cvt_pkrtz(nf[10], nf[11]));
            p1.z = h22i(__builtin_amdgcn_cvt_pkrtz(nf[12], nf[13]));
            p1.w = h22i(__builtin_amdgcn_cvt_pkrtz(nf[14], 1.0f));
            *(int4v*)&xbuf[wid][cb][lane * 8] = p0;
            *(int4v*)&xbuf[wid][cb][lane * 8 + 4] = p1;
        }

        for (int to = 32; to < 64; to += 8)
#pragma unroll
            for (int u = 0; u < 8; ++u) step(tc + to + u);
    }
    h_last[b * HH + lane] = h;
}

// Decoder: one 16x16x64 tile per wave (16 consecutive (b,t) rows of one batch).
// hs read: 2KB contiguous per wave; out store: 704B contiguous per tile.
__global__ __launch_bounds__(256) void rnn_decode(
    const _Float16* __restrict__ hs, const float* __restrict__ W_dec,
    const float* __restrict__ b_dec, float* __restrict__ out)
{
    __shared__ __align__(16) _Float16 wl[16 * HH];
    const int tid = threadIdx.x;
    for (int i = tid; i < 16 * HH; i += 256)
        wl[i] = (_Float16)((i < OO * HH) ? W_dec[i] : 0.0f);
    __syncthreads();

    const int lane = tid & 63;
    const int wid  = tid >> 6;
    const int col  = lane & 15;
    const int quad = lane >> 4;
    const float bd = (col < OO) ? b_dec[col] : 0.0f;

    half8 bf0 = *(const half8*)&wl[col * HH + quad * 8];
    half8 bf1 = *(const half8*)&wl[col * HH + 32 + quad * 8];

    const size_t tile = (size_t)blockIdx.x * 4 + wid;   // 0..32767
    const size_t btb = tile * 16;
    const _Float16* ap = hs + (btb + (size_t)col) * HH + quad * 8;
    half8 a0 = *(const half8*)ap;
    half8 a1 = *(const half8*)(ap + 32);

    floatx4 acc = {0.0f, 0.0f, 0.0f, 0.0f};
    acc = __builtin_amdgcn_mfma_f32_16x16x32_f16(a0, bf0, acc, 0, 0, 0);
    acc = __builtin_amdgcn_mfma_f32_16x16x32_f16(a1, bf1, acc, 0, 0, 0);

    if (col < OO) {
#pragma unroll
        for (int r = 0; r < 4; ++r) {
            const size_t row = btb + (size_t)(quad * 4 + r);
            out[row * OO + col] = fmaxf(acc[r] + bd, 0.0f);
        }
    }
}

extern "C" void kernel_launch(void* const* d_in, const int* in_sizes, int n_in,
                              void* d_out, int out_size, void* d_ws, size_t ws_size,
                              hipStream_t stream) {
    const float* x     = (const float*)d_in[0];
    const float* W_ih  = (const float*)d_in[1];
    const float* b_ih  = (const float*)d_in[2];
    const float* W_hh  = (const float*)d_in[3];
    const float* b_hh  = (const float*)d_in[4];
    const float* W_dec = (const float*)d_in[5];
    const float* b_dec = (const float*)d_in[6];

    float* out    = (float*)d_out;
    float* h_last = out + (size_t)BB * TT * OO;   // second tuple output
    _Float16* hs  = (_Float16*)d_ws;              // [B][T][H] f16, 64 MiB

    rnn_rec<<<BB / 8, 512, 0, stream>>>(x, W_ih, b_ih, W_hh, b_hh, hs, h_last);
    rnn_decode<<<8192, 256, 0, stream>>>(hs, W_dec, b_dec, out);
}

// Round 4
// 336.250 us; speedup vs baseline: 1.2347x; 1.1040x over previous
//
#include <hip/hip_runtime.h>
#include <hip/hip_fp16.h>
#include <stdint.h>

#define BB 512
#define TT 1024
#define II 15
#define HH 64
#define OO 11

typedef __fp16 half2v __attribute__((ext_vector_type(2)));
typedef float floatx4 __attribute__((ext_vector_type(4)));
typedef int int4v __attribute__((ext_vector_type(4)));

union PK { int i; half2v h; float f; };

__device__ __forceinline__ half2v i2h2(int v) { PK u; u.i = v; return u.h; }
__device__ __forceinline__ int h22i(half2v v) { PK u; u.h = v; return u.i; }

__device__ __forceinline__ float FDOT2(half2v a, half2v b, float c) {
    return __builtin_amdgcn_fdot2(a, b, c, false);
}

__device__ __forceinline__ float lane_xor1(float v) {
    PK u; u.f = v;
    // quad_perm(1,0,3,2) = 0xB1 : lane -> lane^1
    u.i = __builtin_amdgcn_mov_dpp(u.i, 0xB1, 0xF, 0xF, false);
    return u.f;
}

__device__ __forceinline__ float lane_xor2(float v) {
    PK u; u.f = v;
    // quad_perm(2,3,0,1) = 0x4E : lane -> lane^2
    u.i = __builtin_amdgcn_mov_dpp(u.i, 0x4E, 0xF, 0xF, false);
    return u.f;
}

// v6: R0 geometry (512 blocks x 1 wave — best measured rec config, 437cy/step;
// R2/R3 proved wall = per-chain step LATENCY, so chains must not share SIMDs)
// + the DECODER FUSED into the step. The h(t-1) broadcast needed by the
// decoder is already in LDS for the recurrence; decode of step t-1 runs inside
// step t: lane l = (o = l>>2, ks = l&3) reads h-pairs [8ks..8ks+7] via two
// lane-addressed ds_read_b128 (16-lane broadcast per address), 8 v_dot2 with
// per-lane W_dec pairs, quad DPP-reduce (xor1+xor2), bias+relu, one 44B
// contiguous predicated store. This deletes the rnn_decode kernel, its launch
// gap, the 64MiB hs write and its 64MiB re-read (~87us of the 273.5us total)
// for ~25-30 extra issue cyc/step in the rec kernel.
__global__ __launch_bounds__(64) void rnn_rec(
    const float* __restrict__ x, const float* __restrict__ W_ih,
    const float* __restrict__ b_ih, const float* __restrict__ W_hh,
    const float* __restrict__ b_hh, const float* __restrict__ W_dec,
    const float* __restrict__ b_dec, float* __restrict__ out,
    float* __restrict__ h_last)
{
    __shared__ __align__(16) int xbuf[2][64 * 8];  // [buf][step][8 packed pairs]
    __shared__ __align__(16) _Float16 hbuf[64];    // h_t, one f16 per lane
    const int b = blockIdx.x;
    const int lane = threadIdx.x;

    // recurrent weights: whh[p] = (W_hh[lane][2p], W_hh[lane][2p+1])
    half2v whh[32];
#pragma unroll
    for (int p = 0; p < 32; ++p)
        whh[p] = __builtin_amdgcn_cvt_pkrtz(W_hh[lane * HH + 2 * p],
                                            W_hh[lane * HH + 2 * p + 1]);
    // input weights; pair 7 = (w14, bias) matching x pair (x14, 1.0)
    half2v wx[8];
#pragma unroll
    for (int j = 0; j < 7; ++j)
        wx[j] = __builtin_amdgcn_cvt_pkrtz(W_ih[lane * II + 2 * j],
                                           W_ih[lane * II + 2 * j + 1]);
    wx[7] = __builtin_amdgcn_cvt_pkrtz(W_ih[lane * II + 14],
                                       b_ih[lane] + b_hh[lane]);

    // decoder lane role: o = lane>>2 (output col, valid < 11), ks = lane&3
    // (K-slice: h pairs 8ks..8ks+7). wdec[p] = (W_dec[o][2(8ks+p)], ..+1)
    const int od = lane >> 2;
    const int oc = (od < OO) ? od : 0;       // clamp for safe weight loads
    const int ks = lane & 3;
    half2v wdec[8];
#pragma unroll
    for (int p = 0; p < 8; ++p)
        wdec[p] = __builtin_amdgcn_cvt_pkrtz(W_dec[oc * HH + (ks * 8 + p) * 2],
                                             W_dec[oc * HH + (ks * 8 + p) * 2 + 1]);
    const float bd = b_dec[oc];
    const bool dostore = (ks == 0) && (od < OO);
    float* outb = out + (size_t)b * TT * OO + od;   // + t*OO per step

    const float* xb = x + (size_t)b * TT * II;
    const int4v* hb4 = (const int4v*)hbuf;

    // stage chunk 0 into xbuf[0]: lane ts packs x[b][ts][0..14] -> 8 pairs
    {
        float cf[II];
#pragma unroll
        for (int i = 0; i < II; ++i) cf[i] = xb[lane * II + i];
        int4v p0, p1;
        p0.x = h22i(__builtin_amdgcn_cvt_pkrtz(cf[0], cf[1]));
        p0.y = h22i(__builtin_amdgcn_cvt_pkrtz(cf[2], cf[3]));
        p0.z = h22i(__builtin_amdgcn_cvt_pkrtz(cf[4], cf[5]));
        p0.w = h22i(__builtin_amdgcn_cvt_pkrtz(cf[6], cf[7]));
        p1.x = h22i(__builtin_amdgcn_cvt_pkrtz(cf[8], cf[9]));
        p1.y = h22i(__builtin_amdgcn_cvt_pkrtz(cf[10], cf[11]));
        p1.z = h22i(__builtin_amdgcn_cvt_pkrtz(cf[12], cf[13]));
        p1.w = h22i(__builtin_amdgcn_cvt_pkrtz(cf[14], 1.0f));
        *(int4v*)&xbuf[0][lane * 8] = p0;
        *(int4v*)&xbuf[0][lane * 8 + 4] = p1;
    }
    hbuf[lane] = (_Float16)0.0f;    // h(-1) = 0

    // xproj accumulators for step 0 (read back slot 0; wave-synchronous)
    float xa[8];
    {
        const int4v xv0 = *(const int4v*)&xbuf[0][0];
        const int4v xv1 = *(const int4v*)&xbuf[0][4];
        xa[0] = FDOT2(i2h2(xv0.x), wx[0], 0.0f);
        xa[1] = FDOT2(i2h2(xv0.y), wx[1], 0.0f);
        xa[2] = FDOT2(i2h2(xv0.z), wx[2], 0.0f);
        xa[3] = FDOT2(i2h2(xv0.w), wx[3], 0.0f);
        xa[4] = FDOT2(i2h2(xv1.x), wx[4], 0.0f);
        xa[5] = FDOT2(i2h2(xv1.y), wx[5], 0.0f);
        xa[6] = FDOT2(i2h2(xv1.z), wx[6], 0.0f);
        xa[7] = FDOT2(i2h2(xv1.w), wx[7], 0.0f);
    }

    float h = 0.0f;
    int hpk = 0;   // packed (h[lane&~1], h[lane|1]) from previous step (h=0)

    auto step = [&](int t) {
        // decode source reads of h(t-1): lane-addressed 32B at ks*32
        // (16-lane broadcast per address; must precede this step's h-write,
        // guaranteed by program order + aliasing on hbuf)
        const int4v d0 = *(const int4v*)((const char*)hbuf + ks * 32);
        const int4v d1 = *(const int4v*)((const char*)hbuf + ks * 32 + 16);

        // LDS broadcast reads of h(t-1)[16..63]: 6 uniform-address b128
        int4v hb[6];
#pragma unroll
        for (int q = 0; q < 6; ++q) hb[q] = hb4[q + 2];

        // seed with precomputed xproj
        float a0 = xa[0], a1 = xa[1], a2 = xa[2], a3 = xa[3];
        float a4 = xa[4], a5 = xa[5], a6 = xa[6], a7 = xa[7];

        // register-broadcast path: h(t-1)[0..15] pairs live in even lanes'
        // hpk; readlane is wave-synchronous, no memory -> fills the DS stall
        a0 = FDOT2(i2h2(__builtin_amdgcn_readlane(hpk, 0)),  whh[0], a0);
        a1 = FDOT2(i2h2(__builtin_amdgcn_readlane(hpk, 2)),  whh[1], a1);
        a2 = FDOT2(i2h2(__builtin_amdgcn_readlane(hpk, 4)),  whh[2], a2);
        a3 = FDOT2(i2h2(__builtin_amdgcn_readlane(hpk, 6)),  whh[3], a3);
        a4 = FDOT2(i2h2(__builtin_amdgcn_readlane(hpk, 8)),  whh[4], a4);
        a5 = FDOT2(i2h2(__builtin_amdgcn_readlane(hpk, 10)), whh[5], a5);
        a6 = FDOT2(i2h2(__builtin_amdgcn_readlane(hpk, 12)), whh[6], a6);
        a7 = FDOT2(i2h2(__builtin_amdgcn_readlane(hpk, 14)), whh[7], a7);

        // LDS dots: round q consumes hb[q] (pairs 8+4q .. 11+4q)
#pragma unroll
        for (int q = 0; q < 6; ++q) {
            const int base = 8 + 4 * q;
            if ((q & 1) == 0) {
                a0 = FDOT2(i2h2(hb[q].x), whh[base + 0], a0);
                a1 = FDOT2(i2h2(hb[q].y), whh[base + 1], a1);
                a2 = FDOT2(i2h2(hb[q].z), whh[base + 2], a2);
                a3 = FDOT2(i2h2(hb[q].w), whh[base + 3], a3);
            } else {
                a4 = FDOT2(i2h2(hb[q].x), whh[base + 0], a4);
                a5 = FDOT2(i2h2(hb[q].y), whh[base + 1], a5);
                a6 = FDOT2(i2h2(hb[q].z), whh[base + 2], a6);
                a7 = FDOT2(i2h2(hb[q].w), whh[base + 3], a7);
            }
        }
        h = fmaxf(((a0 + a1) + (a2 + a3)) + ((a4 + a5) + (a6 + a7)), 0.0f);
        const _Float16 hf = (_Float16)h;
        hbuf[lane] = hf;                       // publish h(t)

        // x pairs for step t+1 (issued AFTER the h write)
        const int tn = t + 1;
        const int* xp = &xbuf[(tn >> 6) & 1][(tn & 63) * 8];
        const int4v xv0 = *(const int4v*)xp;
        const int4v xv1 = *(const int4v*)(xp + 4);

        // ---- fused decode of out[t-1] from h(t-1) (d0/d1) ----
        float dacc = FDOT2(i2h2(d0.x), wdec[0], 0.0f);
        dacc = FDOT2(i2h2(d0.y), wdec[1], dacc);
        dacc = FDOT2(i2h2(d0.z), wdec[2], dacc);
        dacc = FDOT2(i2h2(d0.w), wdec[3], dacc);
        dacc = FDOT2(i2h2(d1.x), wdec[4], dacc);
        dacc = FDOT2(i2h2(d1.y), wdec[5], dacc);
        dacc = FDOT2(i2h2(d1.z), wdec[6], dacc);
        dacc = FDOT2(i2h2(d1.w), wdec[7], dacc);
        dacc += lane_xor1(dacc);               // quad reduce over ks
        dacc += lane_xor2(dacc);
        if (dostore) {
            const int tm = (t > 0) ? (t - 1) : 0;   // t=0 garbage overwritten at t=1
            outb[(size_t)tm * OO] = fmaxf(dacc + bd, 0.0f);
        }

        // pack pair for next step's readlane path (off the DS pipe)
        hpk = h22i(__builtin_amdgcn_cvt_pkrtz(h, lane_xor1(h)));

        // xproj for t+1 (consumes xv late; fills residual stall)
        xa[0] = FDOT2(i2h2(xv0.x), wx[0], 0.0f);
        xa[1] = FDOT2(i2h2(xv0.y), wx[1], 0.0f);
        xa[2] = FDOT2(i2h2(xv0.z), wx[2], 0.0f);
        xa[3] = FDOT2(i2h2(xv0.w), wx[3], 0.0f);
        xa[4] = FDOT2(i2h2(xv1.x), wx[4], 0.0f);
        xa[5] = FDOT2(i2h2(xv1.y), wx[5], 0.0f);
        xa[6] = FDOT2(i2h2(xv1.z), wx[6], 0.0f);
        xa[7] = FDOT2(i2h2(xv1.w), wx[7], 0.0f);
    };

    for (int tc = 0; tc < TT; tc += 64) {
        // global prefetch of the next chunk (re-reads current on the last one)
        const int tnb = (tc + 64 < TT) ? (tc + 64) : tc;
        float nf[II];
#pragma unroll
        for (int i = 0; i < II; ++i)
            nf[i] = xb[(size_t)(tnb + lane) * II + i];

        for (int to = 0; to < 32; to += 8)
#pragma unroll
            for (int u = 0; u < 8; ++u) step(tc + to + u);

        // commit prefetched chunk into the other xbuf half (t+1 reads touch
        // it only from ts=63; committed here at ts=32)
        {
            const int cb = ((tc >> 6) + 1) & 1;
            int4v p0, p1;
            p0.x = h22i(__builtin_amdgcn_cvt_pkrtz(nf[0], nf[1]));
            p0.y = h22i(__builtin_amdgcn_cvt_pkrtz(nf[2], nf[3]));
            p0.z = h22i(__builtin_amdgcn_cvt_pkrtz(nf[4], nf[5]));
            p0.w = h22i(__builtin_amdgcn_cvt_pkrtz(nf[6], nf[7]));
            p1.x = h22i(__builtin_amdgcn_cvt_pkrtz(nf[8], nf[9]));
            p1.y = h22i(__builtin_amdgcn_cvt_pkrtz(nf[10], nf[11]));
            p1.z = h22i(__builtin_amdgcn_cvt_pkrtz(nf[12], nf[13]));
            p1.w = h22i(__builtin_amdgcn_cvt_pkrtz(nf[14], 1.0f));
            *(int4v*)&xbuf[cb][lane * 8] = p0;
            *(int4v*)&xbuf[cb][lane * 8 + 4] = p1;
        }

        for (int to = 32; to < 64; to += 8)
#pragma unroll
            for (int u = 0; u < 8; ++u) step(tc + to + u);
    }

    // tail: decode out[T-1] from h(T-1) (published by the last step)
    {
        const int4v d0 = *(const int4v*)((const char*)hbuf + ks * 32);
        const int4v d1 = *(const int4v*)((const char*)hbuf + ks * 32 + 16);
        float dacc = FDOT2(i2h2(d0.x), wdec[0], 0.0f);
        dacc = FDOT2(i2h2(d0.y), wdec[1], dacc);
        dacc = FDOT2(i2h2(d0.z), wdec[2], dacc);
        dacc = FDOT2(i2h2(d0.w), wdec[3], dacc);
        dacc = FDOT2(i2h2(d1.x), wdec[4], dacc);
        dacc = FDOT2(i2h2(d1.y), wdec[5], dacc);
        dacc = FDOT2(i2h2(d1.z), wdec[6], dacc);
        dacc = FDOT2(i2h2(d1.w), wdec[7], dacc);
        dacc += lane_xor1(dacc);
        dacc += lane_xor2(dacc);
        if (dostore)
            outb[(size_t)(TT - 1) * OO] = fmaxf(dacc + bd, 0.0f);
    }

    h_last[b * HH + lane] = h;
}

extern "C" void kernel_launch(void* const* d_in, const int* in_sizes, int n_in,
                              void* d_out, int out_size, void* d_ws, size_t ws_size,
                              hipStream_t stream) {
    const float* x     = (const float*)d_in[0];
    const float* W_ih  = (const float*)d_in[1];
    const float* b_ih  = (const float*)d_in[2];
    const float* W_hh  = (const float*)d_in[3];
    const float* b_hh  = (const float*)d_in[4];
    const float* W_dec = (const float*)d_in[5];
    const float* b_dec = (const float*)d_in[6];

    float* out    = (float*)d_out;
    float* h_last = out + (size_t)BB * TT * OO;   // second tuple output

    rnn_rec<<<BB, 64, 0, stream>>>(x, W_ih, b_ih, W_hh, b_hh,
                                   W_dec, b_dec, out, h_last);
}

// Round 5
// 259.064 us; speedup vs baseline: 1.6025x; 1.2979x over previous
//
#include <hip/hip_runtime.h>
#include <hip/hip_fp16.h>
#include <stdint.h>

#define BB 512
#define TT 1024
#define II 15
#define HH 64
#define OO 11

typedef __fp16 half2v __attribute__((ext_vector_type(2)));
typedef float floatx4 __attribute__((ext_vector_type(4)));
typedef int int4v __attribute__((ext_vector_type(4)));

union PK { int i; half2v h; float f; };

__device__ __forceinline__ half2v i2h2(int v) { PK u; u.i = v; return u.h; }
__device__ __forceinline__ int h22i(half2v v) { PK u; u.h = v; return u.i; }

__device__ __forceinline__ float FDOT2(half2v a, half2v b, float c) {
    return __builtin_amdgcn_fdot2(a, b, c, false);
}

__device__ __forceinline__ float lane_xor1(float v) {
    PK u; u.f = v;
    // quad_perm(1,0,3,2) = 0xB1 : lane -> lane^1
    u.i = __builtin_amdgcn_mov_dpp(u.i, 0xB1, 0xF, 0xF, false);
    return u.f;
}

__device__ __forceinline__ float lane_xor2(float v) {
    PK u; u.f = v;
    // quad_perm(2,3,0,1) = 0x4E : lane -> lane^2
    u.i = __builtin_amdgcn_mov_dpp(u.i, 0x4E, 0xF, 0xF, false);
    return u.f;
}

// Drain LDS ops, then workgroup barrier (safe in wave-uniform branches;
// every wave executes exactly TT/64 = 16 of these).
__device__ __forceinline__ void block_sync() {
    asm volatile("s_waitcnt lgkmcnt(0)" ::: "memory");
    __builtin_amdgcn_s_barrier();
}

// v7: wave-specialized producer/consumer.
// R4 showed the fused decode costs +196 cyc on the SERIAL rec path (437->633);
// R3 showed same-SIMD co-residency costs +50%; R0's rec body (437 cyc/step) is
// the best measured. So: block = 256 thr = 4 waves on 4 SIMDs of ONE CU
// (256 blocks -> exactly 1 block/CU, rec waves never share a SIMD).
//   wave 0,1: the UNMODIFIED R0 recurrence for batch 2*blk+w, publishing h(t)
//             into a 128-slot LDS ring (slot t&127) instead of hbuf; the
//             per-step hs global store is deleted (hs workspace gone).
//   wave 2,3: R4's verified decode body, consuming ring slots with a 64-step
//             lag (ring halves double-buffer), storing out[t] directly.
// Sync: one barrier per 64-step chunk (16 per wave, equal counts). Decode has
// ~28K cyc slack per chunk for ~2K cyc work -> barrier is free for rec waves.
__global__ __launch_bounds__(256) void rnn_fused(
    const float* __restrict__ x, const float* __restrict__ W_ih,
    const float* __restrict__ b_ih, const float* __restrict__ W_hh,
    const float* __restrict__ b_hh, const float* __restrict__ W_dec,
    const float* __restrict__ b_dec, float* __restrict__ out,
    float* __restrict__ h_last)
{
    __shared__ __align__(16) int xbuf[2][2][64 * 8];        // 8 KiB
    __shared__ __align__(16) _Float16 hring[2][128][HH];    // 32 KiB
    const int tid  = threadIdx.x;
    const int lane = tid & 63;
    const int wid  = tid >> 6;

    if (wid < 2) {
        // ---------------- recurrence producer (R0 body) ----------------
        const int w = wid;
        const int b = blockIdx.x * 2 + w;

        // recurrent weights: whh[p] = (W_hh[lane][2p], W_hh[lane][2p+1])
        half2v whh[32];
#pragma unroll
        for (int p = 0; p < 32; ++p)
            whh[p] = __builtin_amdgcn_cvt_pkrtz(W_hh[lane * HH + 2 * p],
                                                W_hh[lane * HH + 2 * p + 1]);
        // input weights; pair 7 = (w14, bias) matching x pair (x14, 1.0)
        half2v wx[8];
#pragma unroll
        for (int j = 0; j < 7; ++j)
            wx[j] = __builtin_amdgcn_cvt_pkrtz(W_ih[lane * II + 2 * j],
                                               W_ih[lane * II + 2 * j + 1]);
        wx[7] = __builtin_amdgcn_cvt_pkrtz(W_ih[lane * II + 14],
                                           b_ih[lane] + b_hh[lane]);

        const float* xb = x + (size_t)b * TT * II;

        // stage chunk 0 into xbuf[w][0]: lane ts packs x[b][ts][0..14] -> 8 pairs
        {
            float cf[II];
#pragma unroll
            for (int i = 0; i < II; ++i) cf[i] = xb[lane * II + i];
            int4v p0, p1;
            p0.x = h22i(__builtin_amdgcn_cvt_pkrtz(cf[0], cf[1]));
            p0.y = h22i(__builtin_amdgcn_cvt_pkrtz(cf[2], cf[3]));
            p0.z = h22i(__builtin_amdgcn_cvt_pkrtz(cf[4], cf[5]));
            p0.w = h22i(__builtin_amdgcn_cvt_pkrtz(cf[6], cf[7]));
            p1.x = h22i(__builtin_amdgcn_cvt_pkrtz(cf[8], cf[9]));
            p1.y = h22i(__builtin_amdgcn_cvt_pkrtz(cf[10], cf[11]));
            p1.z = h22i(__builtin_amdgcn_cvt_pkrtz(cf[12], cf[13]));
            p1.w = h22i(__builtin_amdgcn_cvt_pkrtz(cf[14], 1.0f));
            *(int4v*)&xbuf[w][0][lane * 8] = p0;
            *(int4v*)&xbuf[w][0][lane * 8 + 4] = p1;
        }
        hring[w][127][lane] = (_Float16)0.0f;    // h(-1) = 0 lives in slot 127

        // xproj accumulators for step 0 (read back slot 0; wave-synchronous)
        float xa[8];
        {
            const int4v xv0 = *(const int4v*)&xbuf[w][0][0];
            const int4v xv1 = *(const int4v*)&xbuf[w][0][4];
            xa[0] = FDOT2(i2h2(xv0.x), wx[0], 0.0f);
            xa[1] = FDOT2(i2h2(xv0.y), wx[1], 0.0f);
            xa[2] = FDOT2(i2h2(xv0.z), wx[2], 0.0f);
            xa[3] = FDOT2(i2h2(xv0.w), wx[3], 0.0f);
            xa[4] = FDOT2(i2h2(xv1.x), wx[4], 0.0f);
            xa[5] = FDOT2(i2h2(xv1.y), wx[5], 0.0f);
            xa[6] = FDOT2(i2h2(xv1.z), wx[6], 0.0f);
            xa[7] = FDOT2(i2h2(xv1.w), wx[7], 0.0f);
        }

        float h = 0.0f;
        int hpk = 0;   // packed (h[lane&~1], h[lane|1]) from prev step (h=0)

        auto step = [&](int t) {
            // LDS broadcast reads of h(t-1)[16..63] from ring slot (t-1)&127
            const int4v* hb4 = (const int4v*)&hring[w][(t + 127) & 127][0];
            int4v hb[6];
#pragma unroll
            for (int q = 0; q < 6; ++q) hb[q] = hb4[q + 2];

            // seed with precomputed xproj
            float a0 = xa[0], a1 = xa[1], a2 = xa[2], a3 = xa[3];
            float a4 = xa[4], a5 = xa[5], a6 = xa[6], a7 = xa[7];

            // register-broadcast path: h(t-1)[0..15] pairs live in even lanes'
            // hpk; readlane is wave-synchronous -> fills the DS stall
            a0 = FDOT2(i2h2(__builtin_amdgcn_readlane(hpk, 0)),  whh[0], a0);
            a1 = FDOT2(i2h2(__builtin_amdgcn_readlane(hpk, 2)),  whh[1], a1);
            a2 = FDOT2(i2h2(__builtin_amdgcn_readlane(hpk, 4)),  whh[2], a2);
            a3 = FDOT2(i2h2(__builtin_amdgcn_readlane(hpk, 6)),  whh[3], a3);
            a4 = FDOT2(i2h2(__builtin_amdgcn_readlane(hpk, 8)),  whh[4], a4);
            a5 = FDOT2(i2h2(__builtin_amdgcn_readlane(hpk, 10)), whh[5], a5);
            a6 = FDOT2(i2h2(__builtin_amdgcn_readlane(hpk, 12)), whh[6], a6);
            a7 = FDOT2(i2h2(__builtin_amdgcn_readlane(hpk, 14)), whh[7], a7);

            // LDS dots: round q consumes hb[q] (pairs 8+4q .. 11+4q)
#pragma unroll
            for (int q = 0; q < 6; ++q) {
                const int base = 8 + 4 * q;
                if ((q & 1) == 0) {
                    a0 = FDOT2(i2h2(hb[q].x), whh[base + 0], a0);
                    a1 = FDOT2(i2h2(hb[q].y), whh[base + 1], a1);
                    a2 = FDOT2(i2h2(hb[q].z), whh[base + 2], a2);
                    a3 = FDOT2(i2h2(hb[q].w), whh[base + 3], a3);
                } else {
                    a4 = FDOT2(i2h2(hb[q].x), whh[base + 0], a4);
                    a5 = FDOT2(i2h2(hb[q].y), whh[base + 1], a5);
                    a6 = FDOT2(i2h2(hb[q].z), whh[base + 2], a6);
                    a7 = FDOT2(i2h2(hb[q].w), whh[base + 3], a7);
                }
            }
            h = fmaxf(((a0 + a1) + (a2 + a3)) + ((a4 + a5) + (a6 + a7)), 0.0f);
            const _Float16 hf = (_Float16)h;
            hring[w][t & 127][lane] = hf;          // publish h(t) to ring

            // x pairs for step t+1 (issued AFTER the h write)
            const int tn = t + 1;
            const int* xp = &xbuf[w][(tn >> 6) & 1][(tn & 63) * 8];
            const int4v xv0 = *(const int4v*)xp;
            const int4v xv1 = *(const int4v*)(xp + 4);

            // pack pair for next step's readlane path (off the DS pipe)
            hpk = h22i(__builtin_amdgcn_cvt_pkrtz(h, lane_xor1(h)));

            // xproj for t+1 (consumes xv late; fills residual stall)
            xa[0] = FDOT2(i2h2(xv0.x), wx[0], 0.0f);
            xa[1] = FDOT2(i2h2(xv0.y), wx[1], 0.0f);
            xa[2] = FDOT2(i2h2(xv0.z), wx[2], 0.0f);
            xa[3] = FDOT2(i2h2(xv0.w), wx[3], 0.0f);
            xa[4] = FDOT2(i2h2(xv1.x), wx[4], 0.0f);
            xa[5] = FDOT2(i2h2(xv1.y), wx[5], 0.0f);
            xa[6] = FDOT2(i2h2(xv1.z), wx[6], 0.0f);
            xa[7] = FDOT2(i2h2(xv1.w), wx[7], 0.0f);
        };

        for (int tc = 0; tc < TT; tc += 64) {
            // global prefetch of the next chunk (re-reads current on last one)
            const int tnb = (tc + 64 < TT) ? (tc + 64) : tc;
            float nf[II];
#pragma unroll
            for (int i = 0; i < II; ++i)
                nf[i] = xb[(size_t)(tnb + lane) * II + i];

            for (int to = 0; to < 32; to += 8)
#pragma unroll
                for (int u = 0; u < 8; ++u) step(tc + to + u);

            // commit prefetched chunk into the other xbuf half
            {
                const int cb = ((tc >> 6) + 1) & 1;
                int4v p0, p1;
                p0.x = h22i(__builtin_amdgcn_cvt_pkrtz(nf[0], nf[1]));
                p0.y = h22i(__builtin_amdgcn_cvt_pkrtz(nf[2], nf[3]));
                p0.z = h22i(__builtin_amdgcn_cvt_pkrtz(nf[4], nf[5]));
                p0.w = h22i(__builtin_amdgcn_cvt_pkrtz(nf[6], nf[7]));
                p1.x = h22i(__builtin_amdgcn_cvt_pkrtz(nf[8], nf[9]));
                p1.y = h22i(__builtin_amdgcn_cvt_pkrtz(nf[10], nf[11]));
                p1.z = h22i(__builtin_amdgcn_cvt_pkrtz(nf[12], nf[13]));
                p1.w = h22i(__builtin_amdgcn_cvt_pkrtz(nf[14], 1.0f));
                *(int4v*)&xbuf[w][cb][lane * 8] = p0;
                *(int4v*)&xbuf[w][cb][lane * 8 + 4] = p1;
            }

            for (int to = 32; to < 64; to += 8)
#pragma unroll
                for (int u = 0; u < 8; ++u) step(tc + to + u);

            block_sync();                      // chunk tc ready for consumers
        }
        h_last[b * HH + lane] = h;
    } else {
        // ---------------- decode consumer (R4 body, lagged) ----------------
        const int w = wid - 2;
        const int b = blockIdx.x * 2 + w;

        // lane role: o = lane>>2 (output col, valid < 11), ks = lane&3
        // (K-slice: h pairs 8ks..8ks+7). wdec[p] = (W_dec[o][2(8ks+p)], ..+1)
        const int od = lane >> 2;
        const int oc = (od < OO) ? od : 0;     // clamp for safe weight loads
        const int ks = lane & 3;
        half2v wdec[8];
#pragma unroll
        for (int p = 0; p < 8; ++p)
            wdec[p] = __builtin_amdgcn_cvt_pkrtz(
                W_dec[oc * HH + (ks * 8 + p) * 2],
                W_dec[oc * HH + (ks * 8 + p) * 2 + 1]);
        const float bd = b_dec[oc];
        const bool dostore = (ks == 0) && (od < OO);
        float* outb = out + (size_t)b * TT * OO + od;

        for (int c = 0; c < TT / 64; ++c) {
            block_sync();                      // wait for producer chunk c
#pragma unroll 4
            for (int lt = 0; lt < 64; ++lt) {
                const int t = c * 64 + lt;
                const char* row = (const char*)&hring[w][t & 127][0];
                const int4v d0 = *(const int4v*)(row + ks * 32);
                const int4v d1 = *(const int4v*)(row + ks * 32 + 16);
                float dacc = FDOT2(i2h2(d0.x), wdec[0], 0.0f);
                dacc = FDOT2(i2h2(d0.y), wdec[1], dacc);
                dacc = FDOT2(i2h2(d0.z), wdec[2], dacc);
                dacc = FDOT2(i2h2(d0.w), wdec[3], dacc);
                dacc = FDOT2(i2h2(d1.x), wdec[4], dacc);
                dacc = FDOT2(i2h2(d1.y), wdec[5], dacc);
                dacc = FDOT2(i2h2(d1.z), wdec[6], dacc);
                dacc = FDOT2(i2h2(d1.w), wdec[7], dacc);
                dacc += lane_xor1(dacc);       // quad reduce over ks
                dacc += lane_xor2(dacc);
                if (dostore)
                    outb[(size_t)t * OO] = fmaxf(dacc + bd, 0.0f);
            }
        }
    }
}

extern "C" void kernel_launch(void* const* d_in, const int* in_sizes, int n_in,
                              void* d_out, int out_size, void* d_ws, size_t ws_size,
                              hipStream_t stream) {
    const float* x     = (const float*)d_in[0];
    const float* W_ih  = (const float*)d_in[1];
    const float* b_ih  = (const float*)d_in[2];
    const float* W_hh  = (const float*)d_in[3];
    const float* b_hh  = (const float*)d_in[4];
    const float* W_dec = (const float*)d_in[5];
    const float* b_dec = (const float*)d_in[6];

    float* out    = (float*)d_out;
    float* h_last = out + (size_t)BB * TT * OO;   // second tuple output

    rnn_fused<<<BB / 2, 256, 0, stream>>>(x, W_ih, b_ih, W_hh, b_hh,
                                          W_dec, b_dec, out, h_last);
}